// Round 1
// baseline (26846.948 us; speedup 1.0000x reference)
//
#include <hip/hip_runtime.h>

#define L_SEQ 513
#define DM 768
#define DI 1536
#define DSTATE 16
#define DTRANK 48
#define NCLS 527
#define DEPTH 24

// ---------------- patch embed + cls insert + pos add ----------------
__global__ void patch_embed_kernel(const float* __restrict__ x,
                                   const float* __restrict__ pw,
                                   const float* __restrict__ pb,
                                   const float* __restrict__ cls,
                                   const float* __restrict__ pos,
                                   float* __restrict__ hidden,
                                   float* __restrict__ residual) {
  int c = blockIdx.x * 256 + threadIdx.x;
  int s = blockIdx.y;
  if (c >= DM) return;
  float val;
  if (s == 256) {
    val = cls[c];
  } else {
    int p = s - (s > 256 ? 1 : 0);
    int gy = p >> 6, gx = p & 63;
    const float* xp = x + gy * 16 * 1024 + gx * 16;
    const float* wp = pw + c * 256;
    float acc = pb[c];
#pragma unroll 4
    for (int ky = 0; ky < 16; ++ky)
#pragma unroll
      for (int kx = 0; kx < 16; ++kx)
        acc += xp[ky * 1024 + kx] * wp[ky * 16 + kx];
    val = acc;
  }
  long idx = (long)s * DM + c;
  hidden[idx] = val + pos[idx];
  residual[idx] = 0.f;
}

// ---------------- residual += hidden; hn = rmsnorm(residual)*w ----------------
__global__ void rmsnorm_kernel(const float* __restrict__ hidden,
                               float* __restrict__ residual,
                               float* __restrict__ hn,
                               const float* __restrict__ w) {
  int t = blockIdx.x;
  const float* hrow = hidden + (long)t * DM;
  float* rrow = residual + (long)t * DM;
  float* orow = hn + (long)t * DM;
  int tid = threadIdx.x;  // 256, DM = 3*256
  float vals[3];
  float ss = 0.f;
#pragma unroll
  for (int i = 0; i < 3; ++i) {
    int c = tid + i * 256;
    float v = rrow[c] + hrow[c];
    vals[i] = v;
    rrow[c] = v;
    ss += v * v;
  }
#pragma unroll
  for (int o = 32; o; o >>= 1) ss += __shfl_down(ss, o, 64);
  __shared__ float sacc[4];
  if ((tid & 63) == 0) sacc[tid >> 6] = ss;
  __syncthreads();
  float tot = sacc[0] + sacc[1] + sacc[2] + sacc[3];
  float rs = rsqrtf(tot / (float)DM + 1e-5f);
#pragma unroll
  for (int i = 0; i < 3; ++i) {
    int c = tid + i * 256;
    orow[c] = vals[i] * rs * w[c];
  }
}

// ---------------- generic batched GEMM: C[m][n] = sum_k A[m][k]*B[n][k] ----------------
// If A2 != nullptr, A element is 0.5*(A + A2) (used to fuse (yf+yb)*0.5).
__global__ __launch_bounds__(256) void gemm_tn(
    const float* __restrict__ A, const float* __restrict__ A2,
    const float* __restrict__ B, float* __restrict__ C,
    int M, int N, int K, int lda, int ldb, int ldc,
    long sA, long sB, long sC) {
  int bz = blockIdx.z;
  const float* Ab = A + (long)bz * sA;
  const float* A2b = A2 ? A2 + (long)bz * sA : nullptr;
  const float* Bb = B + (long)bz * sB;
  float* Cb = C + (long)bz * sC;

  __shared__ float As[16][68];
  __shared__ float Bs[16][68];

  int tid = threadIdx.x;
  int tx = tid & 15, ty = tid >> 4;
  int m0 = blockIdx.y * 64, n0 = blockIdx.x * 64;

  float acc[4][4] = {};

  int kl = tid & 15;
  int rl = tid >> 4;
  for (int k0 = 0; k0 < K; k0 += 16) {
    int k = k0 + kl;
#pragma unroll
    for (int j = 0; j < 4; ++j) {
      int r = rl + j * 16;
      int m = m0 + r;
      float av = 0.f;
      if (m < M && k < K) {
        av = Ab[(long)m * lda + k];
        if (A2b) av = 0.5f * (av + A2b[(long)m * lda + k]);
      }
      As[kl][r] = av;
      int n = n0 + r;
      Bs[kl][r] = (n < N && k < K) ? Bb[(long)n * ldb + k] : 0.f;
    }
    __syncthreads();
#pragma unroll
    for (int kk = 0; kk < 16; ++kk) {
      float4 av = *(const float4*)&As[kk][ty * 4];
      float4 bv = *(const float4*)&Bs[kk][tx * 4];
      float a[4] = {av.x, av.y, av.z, av.w};
      float b[4] = {bv.x, bv.y, bv.z, bv.w};
#pragma unroll
      for (int i = 0; i < 4; ++i)
#pragma unroll
        for (int j = 0; j < 4; ++j)
          acc[i][j] += a[i] * b[j];
    }
    __syncthreads();
  }
#pragma unroll
  for (int i = 0; i < 4; ++i) {
    int m = m0 + ty * 4 + i;
    if (m >= M) continue;
#pragma unroll
    for (int j = 0; j < 4; ++j) {
      int n = n0 + tx * 4 + j;
      if (n < N) Cb[(long)m * ldc + n] = acc[i][j];
    }
  }
}

// ---------------- causal depthwise conv (D_CONV=4) + silu, both directions ----------------
// xz layout: (L, 3072) row-major; x channel d at xz[t*3072 + d].
// Output xc layout: (dir, t_scan, DI). For dir=1, t_scan indexes reversed time.
__global__ void conv_silu_kernel(const float* __restrict__ xz,
                                 const float* __restrict__ cw,  // (2, DI, 4)
                                 const float* __restrict__ cb,  // (2, DI)
                                 float* __restrict__ xc) {
  int dir = blockIdx.y;
  int idx = blockIdx.x * 256 + threadIdx.x;  // over L*DI, d fastest
  int d = idx % DI;
  int t = idx / DI;
  const float* w = cw + ((long)dir * DI + d) * 4;
  float acc = cb[dir * DI + d];
#pragma unroll
  for (int k = 0; k < 4; ++k) {
    int tau = t + k - 3;
    if (tau >= 0) {
      int tsrc = dir ? (L_SEQ - 1 - tau) : tau;
      acc += w[k] * xz[(long)tsrc * (2 * DI) + d];
    }
  }
  float s = acc / (1.f + expf(-acc));
  xc[((long)dir * L_SEQ + t) * DI + d] = s;
}

// ---------------- selective scan, thread per (d, n), 16-lane reduce ----------------
__global__ __launch_bounds__(256) void scan_kernel(
    const float* __restrict__ dtraw,  // (2, L, DI) no bias/softplus yet
    const float* __restrict__ xc,     // (2, L, DI)
    const float* __restrict__ dbl,    // (2, L, 80)
    const float* __restrict__ xz,     // (L, 3072) for z
    const float* __restrict__ db,     // (2, DI)
    const float* __restrict__ A_log,  // (2, DI, 16)
    const float* __restrict__ Dsk,    // (2, DI)
    float* __restrict__ y) {          // (2, L, DI), dir=1 written re-reversed
  int dir = blockIdx.y;
  int tid = threadIdx.x;
  int n = tid & 15;
  int dloc = tid >> 4;
  int d = blockIdx.x * 16 + dloc;

  float negA = -expf(A_log[((long)dir * DI + d) * DSTATE + n]);
  float dbias = db[dir * DI + d];
  float dskip = Dsk[dir * DI + d];
  const float* dtp = dtraw + (long)dir * L_SEQ * DI;
  const float* xcp = xc + (long)dir * L_SEQ * DI;
  const float* dblp = dbl + (long)dir * L_SEQ * 80;
  float* yp = y + (long)dir * L_SEQ * DI;

  float h = 0.f;
  for (int t = 0; t < L_SEQ; ++t) {
    float dtv = dtp[(long)t * DI + d] + dbias;
    dtv = (dtv > 20.f) ? dtv : log1pf(expf(dtv));
    float u = xcp[(long)t * DI + d];
    float Bv = dblp[t * 80 + DTRANK + n];
    float Cv = dblp[t * 80 + DTRANK + DSTATE + n];
    h = h * expf(dtv * negA) + (dtv * u) * Bv;
    float p = h * Cv;
#pragma unroll
    for (int o = 8; o; o >>= 1) p += __shfl_xor(p, o, 64);
    if (n == 0) {
      int tsrc = dir ? (L_SEQ - 1 - t) : t;
      float zv = xz[(long)tsrc * (2 * DI) + DI + d];
      float sz = zv / (1.f + expf(-zv));
      yp[(long)tsrc * DI + d] = (p + dskip * u) * sz;
    }
  }
}

// ---------------- final rmsnorm(token 256) + head, one block per class ----------------
__global__ void head_kernel(const float* __restrict__ residual,
                            const float* __restrict__ hidden,
                            const float* __restrict__ nfw,
                            const float* __restrict__ hw,
                            const float* __restrict__ hb,
                            float* __restrict__ out) {
  int j = blockIdx.x;
  int tid = threadIdx.x;  // 256
  const float* r = residual + (long)256 * DM;
  const float* h = hidden + (long)256 * DM;
  float ss = 0.f, dp = 0.f;
#pragma unroll
  for (int i = 0; i < 3; ++i) {
    int c = tid + i * 256;
    float v = r[c] + h[c];
    ss += v * v;
    dp += v * nfw[c] * hw[(long)j * DM + c];
  }
#pragma unroll
  for (int o = 32; o; o >>= 1) {
    ss += __shfl_down(ss, o, 64);
    dp += __shfl_down(dp, o, 64);
  }
  __shared__ float s1[4], s2[4];
  if ((tid & 63) == 0) {
    s1[tid >> 6] = ss;
    s2[tid >> 6] = dp;
  }
  __syncthreads();
  if (tid == 0) {
    float tot = s1[0] + s1[1] + s1[2] + s1[3];
    float d = s2[0] + s2[1] + s2[2] + s2[3];
    out[j] = d * rsqrtf(tot / (float)DM + 1e-5f) + hb[j];
  }
}

extern "C" void kernel_launch(void* const* d_in, const int* in_sizes, int n_in,
                              void* d_out, int out_size, void* d_ws, size_t ws_size,
                              hipStream_t stream) {
  const float* x        = (const float*)d_in[0];
  const float* patch_w  = (const float*)d_in[1];
  const float* patch_b  = (const float*)d_in[2];
  const float* cls_tok  = (const float*)d_in[3];
  const float* pos_emb  = (const float*)d_in[4];
  const float* in_proj  = (const float*)d_in[5];
  const float* conv_w   = (const float*)d_in[6];
  const float* conv_b   = (const float*)d_in[7];
  const float* xproj_w  = (const float*)d_in[8];
  const float* dtproj_w = (const float*)d_in[9];
  const float* dtproj_b = (const float*)d_in[10];
  const float* A_log    = (const float*)d_in[11];
  const float* D_skip   = (const float*)d_in[12];
  const float* out_proj = (const float*)d_in[13];
  const float* norm_w   = (const float*)d_in[14];
  const float* norm_f_w = (const float*)d_in[15];
  const float* head_w   = (const float*)d_in[16];
  const float* head_b   = (const float*)d_in[17];
  float* out = (float*)d_out;

  float* ws = (float*)d_ws;
  float* residual = ws; ws += (long)L_SEQ * DM;
  float* hidden   = ws; ws += (long)L_SEQ * DM;
  float* hn       = ws; ws += (long)L_SEQ * DM;
  float* xz       = ws; ws += (long)L_SEQ * 2 * DI;
  float* xc       = ws; ws += (long)2 * L_SEQ * DI;
  float* dbl      = ws; ws += (long)2 * L_SEQ * 80;
  float* dtb      = ws; ws += (long)2 * L_SEQ * DI;
  float* yb       = ws; ws += (long)2 * L_SEQ * DI;

  patch_embed_kernel<<<dim3(3, L_SEQ), 256, 0, stream>>>(
      x, patch_w, patch_b, cls_tok, pos_emb, hidden, residual);

  for (int l = 0; l < DEPTH; ++l) {
    const float* ipw = in_proj  + (long)l * 2 * DI * DM;
    const float* cw  = conv_w   + (long)l * 2 * DI * 4;
    const float* cb  = conv_b   + (long)l * 2 * DI;
    const float* xw  = xproj_w  + (long)l * 2 * 80 * DI;
    const float* dw  = dtproj_w + (long)l * 2 * DI * DTRANK;
    const float* db  = dtproj_b + (long)l * 2 * DI;
    const float* Al  = A_log    + (long)l * 2 * DI * DSTATE;
    const float* Dk  = D_skip   + (long)l * 2 * DI;
    const float* opw = out_proj + (long)l * DM * DI;
    const float* nw  = norm_w   + (long)l * DM;

    // residual += hidden; hn = rmsnorm(residual)*nw
    rmsnorm_kernel<<<L_SEQ, 256, 0, stream>>>(hidden, residual, hn, nw);

    // xz(513,3072) = hn(513,768) @ ipw(3072,768)^T
    gemm_tn<<<dim3(48, 9, 1), 256, 0, stream>>>(
        hn, nullptr, ipw, xz, L_SEQ, 2 * DI, DM, DM, DM, 2 * DI, 0, 0, 0);

    // causal conv + silu, both directions (513*1536/256 = 3078 exact)
    conv_silu_kernel<<<dim3(3078, 2), 256, 0, stream>>>(xz, cw, cb, xc);

    // dbl(513,80) = xc(513,1536) @ xw(80,1536)^T  [batched over dir]
    gemm_tn<<<dim3(2, 9, 2), 256, 0, stream>>>(
        xc, nullptr, xw, dbl, L_SEQ, 80, DI, DI, DI, 80,
        (long)L_SEQ * DI, (long)80 * DI, (long)L_SEQ * 80);

    // dtraw(513,1536) = dbl[:, :48](lda=80) @ dw(1536,48)^T  [batched]
    gemm_tn<<<dim3(24, 9, 2), 256, 0, stream>>>(
        dbl, nullptr, dw, dtb, L_SEQ, DI, DTRANK, 80, DTRANK, DI,
        (long)L_SEQ * 80, (long)DI * DTRANK, (long)L_SEQ * DI);

    // selective scan + Dskip + silu(z) gate, both dirs
    scan_kernel<<<dim3(96, 2), 256, 0, stream>>>(
        dtb, xc, dbl, xz, db, Al, Dk, yb);

    // hidden(513,768) = 0.5*(y0+y1)(513,1536) @ opw(768,1536)^T
    gemm_tn<<<dim3(12, 9, 1), 256, 0, stream>>>(
        yb, yb + (long)L_SEQ * DI, opw, hidden,
        L_SEQ, DM, DI, DI, DI, DM, 0, 0, 0);
  }

  head_kernel<<<NCLS, 256, 0, stream>>>(residual, hidden, norm_f_w, head_w, head_b, out);
}

// Round 2
// 13612.747 us; speedup vs baseline: 1.9722x; 1.9722x over previous
//
#include <hip/hip_runtime.h>

#define L_SEQ 513
#define DM 768
#define DI 1536
#define DSTATE 16
#define DTRANK 48
#define NCLS 527
#define DEPTH 24
#define NC 32     // time chunks for parallel scan
#define CLEN 17   // ceil(513/32); NC*CLEN = 544 >= 513

// ---------------- patch embed + cls insert + pos add ----------------
__global__ void patch_embed_kernel(const float* __restrict__ x,
                                   const float* __restrict__ pw,
                                   const float* __restrict__ pb,
                                   const float* __restrict__ cls,
                                   const float* __restrict__ pos,
                                   float* __restrict__ hidden,
                                   float* __restrict__ residual) {
  int c = blockIdx.x * 256 + threadIdx.x;
  int s = blockIdx.y;
  if (c >= DM) return;
  float val;
  if (s == 256) {
    val = cls[c];
  } else {
    int p = s - (s > 256 ? 1 : 0);
    int gy = p >> 6, gx = p & 63;
    const float* xp = x + gy * 16 * 1024 + gx * 16;
    const float* wp = pw + c * 256;
    float acc = pb[c];
#pragma unroll 4
    for (int ky = 0; ky < 16; ++ky)
#pragma unroll
      for (int kx = 0; kx < 16; ++kx)
        acc += xp[ky * 1024 + kx] * wp[ky * 16 + kx];
    val = acc;
  }
  long idx = (long)s * DM + c;
  hidden[idx] = val + pos[idx];
  residual[idx] = 0.f;
}

// ---------------- residual += hidden; hn = rmsnorm(residual)*w ----------------
__global__ void rmsnorm_kernel(const float* __restrict__ hidden,
                               float* __restrict__ residual,
                               float* __restrict__ hn,
                               const float* __restrict__ w) {
  int t = blockIdx.x;
  const float* hrow = hidden + (long)t * DM;
  float* rrow = residual + (long)t * DM;
  float* orow = hn + (long)t * DM;
  int tid = threadIdx.x;  // 256, DM = 3*256
  float vals[3];
  float ss = 0.f;
#pragma unroll
  for (int i = 0; i < 3; ++i) {
    int c = tid + i * 256;
    float v = rrow[c] + hrow[c];
    vals[i] = v;
    rrow[c] = v;
    ss += v * v;
  }
#pragma unroll
  for (int o = 32; o; o >>= 1) ss += __shfl_down(ss, o, 64);
  __shared__ float sacc[4];
  if ((tid & 63) == 0) sacc[tid >> 6] = ss;
  __syncthreads();
  float tot = sacc[0] + sacc[1] + sacc[2] + sacc[3];
  float rs = rsqrtf(tot / (float)DM + 1e-5f);
#pragma unroll
  for (int i = 0; i < 3; ++i) {
    int c = tid + i * 256;
    orow[c] = vals[i] * rs * w[c];
  }
}

// ---------------- generic batched GEMM: C[m][n] = sum_k A[m][k]*B[n][k] ----------------
// A2 != nullptr: A element = 0.5*(A+A2). bias != nullptr: add bias[n].
// act==1: softplus on output.
__global__ __launch_bounds__(256) void gemm_tn(
    const float* __restrict__ A, const float* __restrict__ A2,
    const float* __restrict__ B, float* __restrict__ C,
    int M, int N, int K, int lda, int ldb, int ldc,
    long sA, long sB, long sC,
    const float* __restrict__ bias, long sBias, int act) {
  int bz = blockIdx.z;
  const float* Ab = A + (long)bz * sA;
  const float* A2b = A2 ? A2 + (long)bz * sA : nullptr;
  const float* Bb = B + (long)bz * sB;
  float* Cb = C + (long)bz * sC;
  const float* biasb = bias ? bias + (long)bz * sBias : nullptr;

  __shared__ float As[16][68];
  __shared__ float Bs[16][68];

  int tid = threadIdx.x;
  int tx = tid & 15, ty = tid >> 4;
  int m0 = blockIdx.y * 64, n0 = blockIdx.x * 64;

  float acc[4][4] = {};

  int kl = tid & 15;
  int rl = tid >> 4;
  for (int k0 = 0; k0 < K; k0 += 16) {
    int k = k0 + kl;
#pragma unroll
    for (int j = 0; j < 4; ++j) {
      int r = rl + j * 16;
      int m = m0 + r;
      float av = 0.f;
      if (m < M && k < K) {
        av = Ab[(long)m * lda + k];
        if (A2b) av = 0.5f * (av + A2b[(long)m * lda + k]);
      }
      As[kl][r] = av;
      int n = n0 + r;
      Bs[kl][r] = (n < N && k < K) ? Bb[(long)n * ldb + k] : 0.f;
    }
    __syncthreads();
#pragma unroll
    for (int kk = 0; kk < 16; ++kk) {
      float4 av = *(const float4*)&As[kk][ty * 4];
      float4 bv = *(const float4*)&Bs[kk][tx * 4];
      float a[4] = {av.x, av.y, av.z, av.w};
      float b[4] = {bv.x, bv.y, bv.z, bv.w};
#pragma unroll
      for (int i = 0; i < 4; ++i)
#pragma unroll
        for (int j = 0; j < 4; ++j)
          acc[i][j] += a[i] * b[j];
    }
    __syncthreads();
  }
#pragma unroll
  for (int i = 0; i < 4; ++i) {
    int m = m0 + ty * 4 + i;
    if (m >= M) continue;
#pragma unroll
    for (int j = 0; j < 4; ++j) {
      int n = n0 + tx * 4 + j;
      if (n >= N) continue;
      float v = acc[i][j];
      if (biasb) v += biasb[n];
      if (act == 1) v = (v > 20.f) ? v : log1pf(__expf(v));
      Cb[(long)m * ldc + n] = v;
    }
  }
}

// ---------------- causal depthwise conv (D_CONV=4) + silu, both directions ----------------
__global__ void conv_silu_kernel(const float* __restrict__ xz,
                                 const float* __restrict__ cw,  // (2, DI, 4)
                                 const float* __restrict__ cb,  // (2, DI)
                                 float* __restrict__ xc) {
  int dir = blockIdx.y;
  int idx = blockIdx.x * 256 + threadIdx.x;  // over L*DI, d fastest
  int d = idx % DI;
  int t = idx / DI;
  const float* w = cw + ((long)dir * DI + d) * 4;
  float acc = cb[dir * DI + d];
#pragma unroll
  for (int k = 0; k < 4; ++k) {
    int tau = t + k - 3;
    if (tau >= 0) {
      int tsrc = dir ? (L_SEQ - 1 - tau) : tau;
      acc += w[k] * xz[(long)tsrc * (2 * DI) + d];
    }
  }
  float s = acc / (1.f + __expf(-acc));
  xc[((long)dir * L_SEQ + t) * DI + d] = s;
}

// ---------------- chunked selective scan, pass 1: per-chunk (Q, S) ----------------
// dtv: (2, L, DI) already softplus(dt+bias). Thread per (dir, chunk, d).
__global__ __launch_bounds__(256) void scan_part1(
    const float* __restrict__ dtv_arr,
    const float* __restrict__ xc,
    const float* __restrict__ dbl,   // (2, L, 80)
    const float* __restrict__ A_log, // (2, DI, 16)
    float* __restrict__ part_h,      // (2, NC, DI, 16)
    float* __restrict__ part_S) {    // (2, NC, DI)
  int dir = blockIdx.z;
  int c = blockIdx.y;
  int d = blockIdx.x * 256 + threadIdx.x;
  int t0 = c * CLEN;
  int t1 = min(t0 + CLEN, L_SEQ);

  __shared__ float Bs[CLEN][DSTATE];
  const float* dblp = dbl + (long)dir * L_SEQ * 80;
  for (int i = threadIdx.x; i < (t1 - t0) * DSTATE; i += 256) {
    int tt = i >> 4, n = i & 15;
    Bs[tt][n] = dblp[(long)(t0 + tt) * 80 + DTRANK + n];
  }
  __syncthreads();

  float negA[DSTATE], h[DSTATE];
#pragma unroll
  for (int n = 0; n < DSTATE; ++n) {
    negA[n] = -__expf(A_log[((long)dir * DI + d) * DSTATE + n]);
    h[n] = 0.f;
  }
  const float* dtp = dtv_arr + (long)dir * L_SEQ * DI;
  const float* xcp = xc + (long)dir * L_SEQ * DI;

  float S = 0.f;
  float dt_c = 0.f, u_c = 0.f;
  if (t0 < t1) {
    dt_c = dtp[(long)t0 * DI + d];
    u_c = xcp[(long)t0 * DI + d];
  }
  for (int t = t0; t < t1; ++t) {
    float dt_n = 0.f, u_n = 0.f;
    if (t + 1 < t1) {
      dt_n = dtp[(long)(t + 1) * DI + d];
      u_n = xcp[(long)(t + 1) * DI + d];
    }
    S += dt_c;
    float du = dt_c * u_c;
    int tt = t - t0;
#pragma unroll
    for (int n = 0; n < DSTATE; ++n)
      h[n] = h[n] * __expf(dt_c * negA[n]) + du * Bs[tt][n];
    dt_c = dt_n;
    u_c = u_n;
  }
  long base = ((long)dir * NC + c) * DI + d;
  part_S[base] = S;
#pragma unroll
  for (int n = 0; n < DSTATE; ++n) part_h[base * DSTATE + n] = h[n];
}

// ---------------- fix-up: chunk-local (Q,S) -> chunk-start states (in place) ----------------
__global__ void scan_fix(const float* __restrict__ A_log,
                         const float* __restrict__ part_S,
                         float* __restrict__ part_h) {
  int idx = blockIdx.x * 256 + threadIdx.x;  // (dir, d, n), n fastest
  int n = idx & 15;
  int d = (idx >> 4) % DI;
  int dir = (idx >> 4) / DI;
  float negA = -__expf(A_log[((long)dir * DI + d) * DSTATE + n]);
  float h = 0.f;
  for (int c = 0; c < NC; ++c) {
    long base = ((long)dir * NC + c) * DI + d;
    float S = part_S[base];
    float q = part_h[base * DSTATE + n];
    part_h[base * DSTATE + n] = h;  // becomes hstart for chunk c
    h = h * __expf(negA * S) + q;
  }
}

// ---------------- pass 2: re-scan from hstart, emit gated y ----------------
__global__ __launch_bounds__(256) void scan_part2(
    const float* __restrict__ dtv_arr,
    const float* __restrict__ xc,
    const float* __restrict__ dbl,
    const float* __restrict__ xz,      // (L, 3072) for z
    const float* __restrict__ A_log,
    const float* __restrict__ Dsk,     // (2, DI)
    const float* __restrict__ part_h,  // hstart
    float* __restrict__ y) {           // (2, L_orig, DI)
  int dir = blockIdx.z;
  int c = blockIdx.y;
  int d = blockIdx.x * 256 + threadIdx.x;
  int t0 = c * CLEN;
  int t1 = min(t0 + CLEN, L_SEQ);

  __shared__ float Bs[CLEN][DSTATE];
  __shared__ float Cs[CLEN][DSTATE];
  const float* dblp = dbl + (long)dir * L_SEQ * 80;
  for (int i = threadIdx.x; i < (t1 - t0) * 2 * DSTATE; i += 256) {
    int tt = i >> 5, j = i & 31;
    float v = dblp[(long)(t0 + tt) * 80 + DTRANK + j];
    if (j < DSTATE) Bs[tt][j] = v; else Cs[tt][j - DSTATE] = v;
  }
  __syncthreads();

  float negA[DSTATE], h[DSTATE];
  long base = ((long)dir * NC + c) * DI + d;
#pragma unroll
  for (int n = 0; n < DSTATE; ++n) {
    negA[n] = -__expf(A_log[((long)dir * DI + d) * DSTATE + n]);
    h[n] = part_h[base * DSTATE + n];
  }
  float dskip = Dsk[dir * DI + d];
  const float* dtp = dtv_arr + (long)dir * L_SEQ * DI;
  const float* xcp = xc + (long)dir * L_SEQ * DI;

  float dt_c = 0.f, u_c = 0.f;
  if (t0 < t1) {
    dt_c = dtp[(long)t0 * DI + d];
    u_c = xcp[(long)t0 * DI + d];
  }
  for (int t = t0; t < t1; ++t) {
    float dt_n = 0.f, u_n = 0.f;
    if (t + 1 < t1) {
      dt_n = dtp[(long)(t + 1) * DI + d];
      u_n = xcp[(long)(t + 1) * DI + d];
    }
    float du = dt_c * u_c;
    int tt = t - t0;
    float acc = 0.f;
#pragma unroll
    for (int n = 0; n < DSTATE; ++n) {
      h[n] = h[n] * __expf(dt_c * negA[n]) + du * Bs[tt][n];
      acc += h[n] * Cs[tt][n];
    }
    int tsrc = dir ? (L_SEQ - 1 - t) : t;
    float zv = xz[(long)tsrc * (2 * DI) + DI + d];
    float sz = zv / (1.f + __expf(-zv));
    y[((long)dir * L_SEQ + tsrc) * DI + d] = (acc + dskip * u_c) * sz;
    dt_c = dt_n;
    u_c = u_n;
  }
}

// ---------------- final rmsnorm(token 256) + head ----------------
__global__ void head_kernel(const float* __restrict__ residual,
                            const float* __restrict__ hidden,
                            const float* __restrict__ nfw,
                            const float* __restrict__ hw,
                            const float* __restrict__ hb,
                            float* __restrict__ out) {
  int j = blockIdx.x;
  int tid = threadIdx.x;  // 256
  const float* r = residual + (long)256 * DM;
  const float* h = hidden + (long)256 * DM;
  float ss = 0.f, dp = 0.f;
#pragma unroll
  for (int i = 0; i < 3; ++i) {
    int c = tid + i * 256;
    float v = r[c] + h[c];
    ss += v * v;
    dp += v * nfw[c] * hw[(long)j * DM + c];
  }
#pragma unroll
  for (int o = 32; o; o >>= 1) {
    ss += __shfl_down(ss, o, 64);
    dp += __shfl_down(dp, o, 64);
  }
  __shared__ float s1[4], s2[4];
  if ((tid & 63) == 0) {
    s1[tid >> 6] = ss;
    s2[tid >> 6] = dp;
  }
  __syncthreads();
  if (tid == 0) {
    float tot = s1[0] + s1[1] + s1[2] + s1[3];
    float d = s2[0] + s2[1] + s2[2] + s2[3];
    out[j] = d * rsqrtf(tot / (float)DM + 1e-5f) + hb[j];
  }
}

extern "C" void kernel_launch(void* const* d_in, const int* in_sizes, int n_in,
                              void* d_out, int out_size, void* d_ws, size_t ws_size,
                              hipStream_t stream) {
  const float* x        = (const float*)d_in[0];
  const float* patch_w  = (const float*)d_in[1];
  const float* patch_b  = (const float*)d_in[2];
  const float* cls_tok  = (const float*)d_in[3];
  const float* pos_emb  = (const float*)d_in[4];
  const float* in_proj  = (const float*)d_in[5];
  const float* conv_w   = (const float*)d_in[6];
  const float* conv_b   = (const float*)d_in[7];
  const float* xproj_w  = (const float*)d_in[8];
  const float* dtproj_w = (const float*)d_in[9];
  const float* dtproj_b = (const float*)d_in[10];
  const float* A_log    = (const float*)d_in[11];
  const float* D_skip   = (const float*)d_in[12];
  const float* out_proj = (const float*)d_in[13];
  const float* norm_w   = (const float*)d_in[14];
  const float* norm_f_w = (const float*)d_in[15];
  const float* head_w   = (const float*)d_in[16];
  const float* head_b   = (const float*)d_in[17];
  float* out = (float*)d_out;

  float* ws = (float*)d_ws;
  float* residual = ws; ws += (long)L_SEQ * DM;
  float* hidden   = ws; ws += (long)L_SEQ * DM;
  float* hn       = ws; ws += (long)L_SEQ * DM;
  float* xz       = ws; ws += (long)L_SEQ * 2 * DI;
  float* xc       = ws; ws += (long)2 * L_SEQ * DI;
  float* dbl      = ws; ws += (long)2 * L_SEQ * 80;
  float* dtb      = ws; ws += (long)2 * L_SEQ * DI;
  float* yb       = ws; ws += (long)2 * L_SEQ * DI;
  float* part_h   = ws; ws += (long)2 * NC * DI * DSTATE;
  float* part_S   = ws; ws += (long)2 * NC * DI;

  patch_embed_kernel<<<dim3(3, L_SEQ), 256, 0, stream>>>(
      x, patch_w, patch_b, cls_tok, pos_emb, hidden, residual);

  for (int l = 0; l < DEPTH; ++l) {
    const float* ipw = in_proj  + (long)l * 2 * DI * DM;
    const float* cw  = conv_w   + (long)l * 2 * DI * 4;
    const float* cb  = conv_b   + (long)l * 2 * DI;
    const float* xw  = xproj_w  + (long)l * 2 * 80 * DI;
    const float* dw  = dtproj_w + (long)l * 2 * DI * DTRANK;
    const float* db  = dtproj_b + (long)l * 2 * DI;
    const float* Al  = A_log    + (long)l * 2 * DI * DSTATE;
    const float* Dk  = D_skip   + (long)l * 2 * DI;
    const float* opw = out_proj + (long)l * DM * DI;
    const float* nw  = norm_w   + (long)l * DM;

    rmsnorm_kernel<<<L_SEQ, 256, 0, stream>>>(hidden, residual, hn, nw);

    // xz(513,3072) = hn(513,768) @ ipw(3072,768)^T
    gemm_tn<<<dim3(48, 9, 1), 256, 0, stream>>>(
        hn, nullptr, ipw, xz, L_SEQ, 2 * DI, DM, DM, DM, 2 * DI, 0, 0, 0,
        nullptr, 0, 0);

    conv_silu_kernel<<<dim3(3078, 2), 256, 0, stream>>>(xz, cw, cb, xc);

    // dbl(513,80) = xc(513,1536) @ xw(80,1536)^T  [batched over dir]
    gemm_tn<<<dim3(2, 9, 2), 256, 0, stream>>>(
        xc, nullptr, xw, dbl, L_SEQ, 80, DI, DI, DI, 80,
        (long)L_SEQ * DI, (long)80 * DI, (long)L_SEQ * 80,
        nullptr, 0, 0);

    // dtb(513,1536) = softplus(dbl[:, :48] @ dw^T + db)  [batched]
    gemm_tn<<<dim3(24, 9, 2), 256, 0, stream>>>(
        dbl, nullptr, dw, dtb, L_SEQ, DI, DTRANK, 80, DTRANK, DI,
        (long)L_SEQ * 80, (long)DI * DTRANK, (long)L_SEQ * DI,
        db, DI, 1);

    // chunked selective scan
    scan_part1<<<dim3(DI / 256, NC, 2), 256, 0, stream>>>(
        dtb, xc, dbl, Al, part_h, part_S);
    scan_fix<<<(2 * DI * DSTATE) / 256, 256, 0, stream>>>(Al, part_S, part_h);
    scan_part2<<<dim3(DI / 256, NC, 2), 256, 0, stream>>>(
        dtb, xc, dbl, xz, Al, Dk, part_h, yb);

    // hidden(513,768) = 0.5*(y0+y1)(513,1536) @ opw(768,1536)^T
    gemm_tn<<<dim3(12, 9, 1), 256, 0, stream>>>(
        yb, yb + (long)L_SEQ * DI, opw, hidden,
        L_SEQ, DM, DI, DI, DI, DM, 0, 0, 0,
        nullptr, 0, 0);
  }

  head_kernel<<<NCLS, 256, 0, stream>>>(residual, hidden, norm_f_w, head_w, head_b, out);
}

// Round 3
// 5953.312 us; speedup vs baseline: 4.5096x; 2.2866x over previous
//
#include <hip/hip_runtime.h>

#define L_SEQ 513
#define DM 768
#define DI 1536
#define DSTATE 16
#define DTRANK 48
#define NCLS 527
#define DEPTH 24
#define NC 32     // time chunks for parallel scan
#define CLEN 17   // ceil(513/32); NC*CLEN = 544 >= 513

typedef __bf16 bf16x8 __attribute__((ext_vector_type(8)));
typedef float f32x4 __attribute__((ext_vector_type(4)));

#define MFMA_BF16(A, B, C) __builtin_amdgcn_mfma_f32_16x16x32_bf16(A, B, C, 0, 0, 0)

__device__ inline unsigned short f2bf(float x) {
  unsigned u = __float_as_uint(x);
  return (unsigned short)((u + 0x7FFFu + ((u >> 16) & 1u)) >> 16);
}

// ---------------- patch embed + cls insert + pos add ----------------
__global__ void patch_embed_kernel(const float* __restrict__ x,
                                   const float* __restrict__ pw,
                                   const float* __restrict__ pb,
                                   const float* __restrict__ cls,
                                   const float* __restrict__ pos,
                                   float* __restrict__ hidden,
                                   float* __restrict__ residual) {
  int c = blockIdx.x * 256 + threadIdx.x;
  int s = blockIdx.y;
  if (c >= DM) return;
  float val;
  if (s == 256) {
    val = cls[c];
  } else {
    int p = s - (s > 256 ? 1 : 0);
    int gy = p >> 6, gx = p & 63;
    const float* xp = x + gy * 16 * 1024 + gx * 16;
    const float* wp = pw + c * 256;
    float acc = pb[c];
#pragma unroll 4
    for (int ky = 0; ky < 16; ++ky)
#pragma unroll
      for (int kx = 0; kx < 16; ++kx)
        acc += xp[ky * 1024 + kx] * wp[ky * 16 + kx];
    val = acc;
  }
  long idx = (long)s * DM + c;
  hidden[idx] = val + pos[idx];
  residual[idx] = 0.f;
}

// ---------------- residual += hidden; hn = rmsnorm(residual)*w ----------------
__global__ void rmsnorm_kernel(const float* __restrict__ hidden,
                               float* __restrict__ residual,
                               float* __restrict__ hn,
                               const float* __restrict__ w) {
  int t = blockIdx.x;
  const float* hrow = hidden + (long)t * DM;
  float* rrow = residual + (long)t * DM;
  float* orow = hn + (long)t * DM;
  int tid = threadIdx.x;  // 256, DM = 3*256
  float vals[3];
  float ss = 0.f;
#pragma unroll
  for (int i = 0; i < 3; ++i) {
    int c = tid + i * 256;
    float v = rrow[c] + hrow[c];
    vals[i] = v;
    rrow[c] = v;
    ss += v * v;
  }
#pragma unroll
  for (int o = 32; o; o >>= 1) ss += __shfl_down(ss, o, 64);
  __shared__ float sacc[4];
  if ((tid & 63) == 0) sacc[tid >> 6] = ss;
  __syncthreads();
  float tot = sacc[0] + sacc[1] + sacc[2] + sacc[3];
  float rs = rsqrtf(tot / (float)DM + 1e-5f);
#pragma unroll
  for (int i = 0; i < 3; ++i) {
    int c = tid + i * 256;
    orow[c] = vals[i] * rs * w[c];
  }
}

// ---------------- MFMA split-bf16 GEMM: C[m][n] = sum_k A[m][k]*B[n][k] ----------------
// fp32 in/out, internally A,B split into bf16 hi+lo; C = Ah*Bh + Ah*Bl + Al*Bh.
// A2 != nullptr: A element = 0.5*(A+A2). bias != nullptr: add bias[n]. act==1: softplus.
__global__ __launch_bounds__(256) void gemm_mfma(
    const float* __restrict__ A, const float* __restrict__ A2,
    const float* __restrict__ B, float* __restrict__ C,
    int M, int N, int K, int lda, int ldb, int ldc,
    long sA, long sB, long sC,
    const float* __restrict__ bias, long sBias, int act) {
  int bz = blockIdx.z;
  const float* Ab = A + (long)bz * sA;
  const float* A2b = A2 ? A2 + (long)bz * sA : nullptr;
  const float* Bb = B + (long)bz * sB;
  float* Cb = C + (long)bz * sC;
  const float* biasb = bias ? bias + (long)bz * sBias : nullptr;

  __shared__ unsigned short Ah[64 * 32], Al[64 * 32];
  __shared__ unsigned short Bh[64 * 32], Bl[64 * 32];

  int tid = threadIdx.x;
  int m0 = blockIdx.y * 64, n0 = blockIdx.x * 64;

  // staging mapping: thread -> (row, 4-float k-group)
  int tr = tid >> 3;          // 0..31 (also +32)
  int tk4 = (tid & 7) * 4;    // 0,4,...,28

  // fragment mapping
  int lane = tid & 63;
  int w = tid >> 6;
  int wr = w >> 1, wc = w & 1;
  int fr = lane & 15, kh = lane >> 4;  // kh = k-group for operands, row-group for C
  int rowA0 = wr * 32 + fr, rowA1 = rowA0 + 16;
  int rowB0 = wc * 32 + fr, rowB1 = rowB0 + 16;
  int offA0 = rowA0 * 32 + ((kh ^ ((rowA0 >> 1) & 3)) << 3);
  int offA1 = rowA1 * 32 + ((kh ^ ((rowA1 >> 1) & 3)) << 3);
  int offB0 = rowB0 * 32 + ((kh ^ ((rowB0 >> 1) & 3)) << 3);
  int offB1 = rowB1 * 32 + ((kh ^ ((rowB1 >> 1) & 3)) << 3);

  auto ldA = [&](int row, int kb) -> float4 {
    int m = m0 + row;
    int k = kb + tk4;
    float4 v = make_float4(0.f, 0.f, 0.f, 0.f);
    if (m < M && k < K) {
      const float* q = Ab + (long)m * lda + k;
      if (k + 3 < K) v = *(const float4*)q;
      else {
        v.x = q[0];
        if (k + 1 < K) v.y = q[1];
        if (k + 2 < K) v.z = q[2];
      }
      if (A2b) {
        const float* q2 = A2b + (long)m * lda + k;
        float4 v2 = make_float4(0.f, 0.f, 0.f, 0.f);
        if (k + 3 < K) v2 = *(const float4*)q2;
        else {
          v2.x = q2[0];
          if (k + 1 < K) v2.y = q2[1];
          if (k + 2 < K) v2.z = q2[2];
        }
        v.x = 0.5f * (v.x + v2.x); v.y = 0.5f * (v.y + v2.y);
        v.z = 0.5f * (v.z + v2.z); v.w = 0.5f * (v.w + v2.w);
      }
    }
    return v;
  };
  auto ldB = [&](int row, int kb) -> float4 {
    int n = n0 + row;
    int k = kb + tk4;
    float4 v = make_float4(0.f, 0.f, 0.f, 0.f);
    if (n < N && k < K) {
      const float* q = Bb + (long)n * ldb + k;
      if (k + 3 < K) v = *(const float4*)q;
      else {
        v.x = q[0];
        if (k + 1 < K) v.y = q[1];
        if (k + 2 < K) v.z = q[2];
      }
    }
    return v;
  };
  auto store = [&](unsigned short* H, unsigned short* L, int row, float4 v) {
    int sg = (tk4 >> 3) ^ ((row >> 1) & 3);
    int e = row * 32 + sg * 8 + (tk4 & 4);
    ushort4 hv, lv;
    unsigned short h;
    h = f2bf(v.x); hv.x = h; lv.x = f2bf(v.x - __uint_as_float((unsigned)h << 16));
    h = f2bf(v.y); hv.y = h; lv.y = f2bf(v.y - __uint_as_float((unsigned)h << 16));
    h = f2bf(v.z); hv.z = h; lv.z = f2bf(v.z - __uint_as_float((unsigned)h << 16));
    h = f2bf(v.w); hv.w = h; lv.w = f2bf(v.w - __uint_as_float((unsigned)h << 16));
    *(ushort4*)&H[e] = hv;
    *(ushort4*)&L[e] = lv;
  };

  f32x4 acc00 = {0.f, 0.f, 0.f, 0.f}, acc01 = {0.f, 0.f, 0.f, 0.f};
  f32x4 acc10 = {0.f, 0.f, 0.f, 0.f}, acc11 = {0.f, 0.f, 0.f, 0.f};

  int nsteps = (K + 31) / 32;
  float4 pa0 = ldA(tr, 0), pa1 = ldA(tr + 32, 0);
  float4 pb0 = ldB(tr, 0), pb1 = ldB(tr + 32, 0);
  float4 qa0, qa1, qb0, qb1;

  for (int s = 0; s < nsteps; ++s) {
    __syncthreads();  // previous compute done; LDS free
    if ((s & 1) == 0) {
      store(Ah, Al, tr, pa0); store(Ah, Al, tr + 32, pa1);
      store(Bh, Bl, tr, pb0); store(Bh, Bl, tr + 32, pb1);
      if (s + 1 < nsteps) {
        int kb = (s + 1) * 32;
        qa0 = ldA(tr, kb); qa1 = ldA(tr + 32, kb);
        qb0 = ldB(tr, kb); qb1 = ldB(tr + 32, kb);
      }
    } else {
      store(Ah, Al, tr, qa0); store(Ah, Al, tr + 32, qa1);
      store(Bh, Bl, tr, qb0); store(Bh, Bl, tr + 32, qb1);
      if (s + 1 < nsteps) {
        int kb = (s + 1) * 32;
        pa0 = ldA(tr, kb); pa1 = ldA(tr + 32, kb);
        pb0 = ldB(tr, kb); pb1 = ldB(tr + 32, kb);
      }
    }
    __syncthreads();

    bf16x8 ah0 = __builtin_bit_cast(bf16x8, *(const uint4*)&Ah[offA0]);
    bf16x8 ah1 = __builtin_bit_cast(bf16x8, *(const uint4*)&Ah[offA1]);
    bf16x8 al0 = __builtin_bit_cast(bf16x8, *(const uint4*)&Al[offA0]);
    bf16x8 al1 = __builtin_bit_cast(bf16x8, *(const uint4*)&Al[offA1]);
    bf16x8 bh0 = __builtin_bit_cast(bf16x8, *(const uint4*)&Bh[offB0]);
    bf16x8 bh1 = __builtin_bit_cast(bf16x8, *(const uint4*)&Bh[offB1]);
    bf16x8 bl0 = __builtin_bit_cast(bf16x8, *(const uint4*)&Bl[offB0]);
    bf16x8 bl1 = __builtin_bit_cast(bf16x8, *(const uint4*)&Bl[offB1]);

    acc00 = MFMA_BF16(ah0, bh0, acc00);
    acc00 = MFMA_BF16(ah0, bl0, acc00);
    acc00 = MFMA_BF16(al0, bh0, acc00);
    acc01 = MFMA_BF16(ah0, bh1, acc01);
    acc01 = MFMA_BF16(ah0, bl1, acc01);
    acc01 = MFMA_BF16(al0, bh1, acc01);
    acc10 = MFMA_BF16(ah1, bh0, acc10);
    acc10 = MFMA_BF16(ah1, bl0, acc10);
    acc10 = MFMA_BF16(al1, bh0, acc10);
    acc11 = MFMA_BF16(ah1, bh1, acc11);
    acc11 = MFMA_BF16(ah1, bl1, acc11);
    acc11 = MFMA_BF16(al1, bh1, acc11);
  }

  int mbase = m0 + wr * 32, nbase = n0 + wc * 32;
#define WRITE_FRAG(ACC, MI, NI)                                   \
  {                                                               \
    int n = nbase + (NI)*16 + fr;                                 \
    if (n < N) {                                                  \
      float bv = biasb ? biasb[n] : 0.f;                          \
      _Pragma("unroll")                                           \
      for (int r = 0; r < 4; ++r) {                               \
        int m = mbase + (MI)*16 + kh * 4 + r;                     \
        if (m < M) {                                              \
          float v = ACC[r] + bv;                                  \
          if (act == 1) v = (v > 20.f) ? v : log1pf(__expf(v));   \
          Cb[(long)m * ldc + n] = v;                              \
        }                                                         \
      }                                                           \
    }                                                             \
  }
  WRITE_FRAG(acc00, 0, 0)
  WRITE_FRAG(acc01, 0, 1)
  WRITE_FRAG(acc10, 1, 0)
  WRITE_FRAG(acc11, 1, 1)
#undef WRITE_FRAG
}

// ---------------- causal depthwise conv (D_CONV=4) + silu, both directions ----------------
__global__ void conv_silu_kernel(const float* __restrict__ xz,
                                 const float* __restrict__ cw,  // (2, DI, 4)
                                 const float* __restrict__ cb,  // (2, DI)
                                 float* __restrict__ xc) {
  int dir = blockIdx.y;
  int idx = blockIdx.x * 256 + threadIdx.x;  // over L*DI, d fastest
  int d = idx % DI;
  int t = idx / DI;
  const float* w = cw + ((long)dir * DI + d) * 4;
  float acc = cb[dir * DI + d];
#pragma unroll
  for (int k = 0; k < 4; ++k) {
    int tau = t + k - 3;
    if (tau >= 0) {
      int tsrc = dir ? (L_SEQ - 1 - tau) : tau;
      acc += w[k] * xz[(long)tsrc * (2 * DI) + d];
    }
  }
  float s = acc / (1.f + __expf(-acc));
  xc[((long)dir * L_SEQ + t) * DI + d] = s;
}

// ---------------- chunked selective scan, pass 1: per-chunk (Q, S) ----------------
__global__ __launch_bounds__(256) void scan_part1(
    const float* __restrict__ dtv_arr,
    const float* __restrict__ xc,
    const float* __restrict__ dbl,   // (2, L, 80)
    const float* __restrict__ A_log, // (2, DI, 16)
    float* __restrict__ part_h,      // (2, NC, DI, 16)
    float* __restrict__ part_S) {    // (2, NC, DI)
  int dir = blockIdx.z;
  int c = blockIdx.y;
  int d = blockIdx.x * 256 + threadIdx.x;
  int t0 = c * CLEN;
  int t1 = min(t0 + CLEN, L_SEQ);

  __shared__ float Bs[CLEN][DSTATE];
  const float* dblp = dbl + (long)dir * L_SEQ * 80;
  for (int i = threadIdx.x; i < (t1 - t0) * DSTATE; i += 256) {
    int tt = i >> 4, n = i & 15;
    Bs[tt][n] = dblp[(long)(t0 + tt) * 80 + DTRANK + n];
  }
  __syncthreads();

  float negA[DSTATE], h[DSTATE];
#pragma unroll
  for (int n = 0; n < DSTATE; ++n) {
    negA[n] = -__expf(A_log[((long)dir * DI + d) * DSTATE + n]);
    h[n] = 0.f;
  }
  const float* dtp = dtv_arr + (long)dir * L_SEQ * DI;
  const float* xcp = xc + (long)dir * L_SEQ * DI;

  float S = 0.f;
  float dt_c = 0.f, u_c = 0.f;
  if (t0 < t1) {
    dt_c = dtp[(long)t0 * DI + d];
    u_c = xcp[(long)t0 * DI + d];
  }
  for (int t = t0; t < t1; ++t) {
    float dt_n = 0.f, u_n = 0.f;
    if (t + 1 < t1) {
      dt_n = dtp[(long)(t + 1) * DI + d];
      u_n = xcp[(long)(t + 1) * DI + d];
    }
    S += dt_c;
    float du = dt_c * u_c;
    int tt = t - t0;
#pragma unroll
    for (int n = 0; n < DSTATE; ++n)
      h[n] = h[n] * __expf(dt_c * negA[n]) + du * Bs[tt][n];
    dt_c = dt_n;
    u_c = u_n;
  }
  long base = ((long)dir * NC + c) * DI + d;
  part_S[base] = S;
#pragma unroll
  for (int n = 0; n < DSTATE; ++n) part_h[base * DSTATE + n] = h[n];
}

// ---------------- fix-up: chunk-local (Q,S) -> chunk-start states (in place) ----------------
__global__ void scan_fix(const float* __restrict__ A_log,
                         const float* __restrict__ part_S,
                         float* __restrict__ part_h) {
  int idx = blockIdx.x * 256 + threadIdx.x;  // (dir, d, n), n fastest
  int n = idx & 15;
  int d = (idx >> 4) % DI;
  int dir = (idx >> 4) / DI;
  float negA = -__expf(A_log[((long)dir * DI + d) * DSTATE + n]);
  float h = 0.f;
  for (int c = 0; c < NC; ++c) {
    long base = ((long)dir * NC + c) * DI + d;
    float S = part_S[base];
    float q = part_h[base * DSTATE + n];
    part_h[base * DSTATE + n] = h;  // becomes hstart for chunk c
    h = h * __expf(negA * S) + q;
  }
}

// ---------------- pass 2: re-scan from hstart, emit gated y ----------------
__global__ __launch_bounds__(256) void scan_part2(
    const float* __restrict__ dtv_arr,
    const float* __restrict__ xc,
    const float* __restrict__ dbl,
    const float* __restrict__ xz,      // (L, 3072) for z
    const float* __restrict__ A_log,
    const float* __restrict__ Dsk,     // (2, DI)
    const float* __restrict__ part_h,  // hstart
    float* __restrict__ y) {           // (2, L_orig, DI)
  int dir = blockIdx.z;
  int c = blockIdx.y;
  int d = blockIdx.x * 256 + threadIdx.x;
  int t0 = c * CLEN;
  int t1 = min(t0 + CLEN, L_SEQ);

  __shared__ float Bs[CLEN][DSTATE];
  __shared__ float Cs[CLEN][DSTATE];
  const float* dblp = dbl + (long)dir * L_SEQ * 80;
  for (int i = threadIdx.x; i < (t1 - t0) * 2 * DSTATE; i += 256) {
    int tt = i >> 5, j = i & 31;
    float v = dblp[(long)(t0 + tt) * 80 + DTRANK + j];
    if (j < DSTATE) Bs[tt][j] = v; else Cs[tt][j - DSTATE] = v;
  }
  __syncthreads();

  float negA[DSTATE], h[DSTATE];
  long base = ((long)dir * NC + c) * DI + d;
#pragma unroll
  for (int n = 0; n < DSTATE; ++n) {
    negA[n] = -__expf(A_log[((long)dir * DI + d) * DSTATE + n]);
    h[n] = part_h[base * DSTATE + n];
  }
  float dskip = Dsk[dir * DI + d];
  const float* dtp = dtv_arr + (long)dir * L_SEQ * DI;
  const float* xcp = xc + (long)dir * L_SEQ * DI;

  float dt_c = 0.f, u_c = 0.f;
  if (t0 < t1) {
    dt_c = dtp[(long)t0 * DI + d];
    u_c = xcp[(long)t0 * DI + d];
  }
  for (int t = t0; t < t1; ++t) {
    float dt_n = 0.f, u_n = 0.f;
    if (t + 1 < t1) {
      dt_n = dtp[(long)(t + 1) * DI + d];
      u_n = xcp[(long)(t + 1) * DI + d];
    }
    float du = dt_c * u_c;
    int tt = t - t0;
    float acc = 0.f;
#pragma unroll
    for (int n = 0; n < DSTATE; ++n) {
      h[n] = h[n] * __expf(dt_c * negA[n]) + du * Bs[tt][n];
      acc += h[n] * Cs[tt][n];
    }
    int tsrc = dir ? (L_SEQ - 1 - t) : t;
    float zv = xz[(long)tsrc * (2 * DI) + DI + d];
    float sz = zv / (1.f + __expf(-zv));
    y[((long)dir * L_SEQ + tsrc) * DI + d] = (acc + dskip * u_c) * sz;
    dt_c = dt_n;
    u_c = u_n;
  }
}

// ---------------- final rmsnorm(token 256) + head ----------------
__global__ void head_kernel(const float* __restrict__ residual,
                            const float* __restrict__ hidden,
                            const float* __restrict__ nfw,
                            const float* __restrict__ hw,
                            const float* __restrict__ hb,
                            float* __restrict__ out) {
  int j = blockIdx.x;
  int tid = threadIdx.x;  // 256
  const float* r = residual + (long)256 * DM;
  const float* h = hidden + (long)256 * DM;
  float ss = 0.f, dp = 0.f;
#pragma unroll
  for (int i = 0; i < 3; ++i) {
    int c = tid + i * 256;
    float v = r[c] + h[c];
    ss += v * v;
    dp += v * nfw[c] * hw[(long)j * DM + c];
  }
#pragma unroll
  for (int o = 32; o; o >>= 1) {
    ss += __shfl_down(ss, o, 64);
    dp += __shfl_down(dp, o, 64);
  }
  __shared__ float s1[4], s2[4];
  if ((tid & 63) == 0) {
    s1[tid >> 6] = ss;
    s2[tid >> 6] = dp;
  }
  __syncthreads();
  if (tid == 0) {
    float tot = s1[0] + s1[1] + s1[2] + s1[3];
    float d = s2[0] + s2[1] + s2[2] + s2[3];
    out[j] = d * rsqrtf(tot / (float)DM + 1e-5f) + hb[j];
  }
}

extern "C" void kernel_launch(void* const* d_in, const int* in_sizes, int n_in,
                              void* d_out, int out_size, void* d_ws, size_t ws_size,
                              hipStream_t stream) {
  const float* x        = (const float*)d_in[0];
  const float* patch_w  = (const float*)d_in[1];
  const float* patch_b  = (const float*)d_in[2];
  const float* cls_tok  = (const float*)d_in[3];
  const float* pos_emb  = (const float*)d_in[4];
  const float* in_proj  = (const float*)d_in[5];
  const float* conv_w   = (const float*)d_in[6];
  const float* conv_b   = (const float*)d_in[7];
  const float* xproj_w  = (const float*)d_in[8];
  const float* dtproj_w = (const float*)d_in[9];
  const float* dtproj_b = (const float*)d_in[10];
  const float* A_log    = (const float*)d_in[11];
  const float* D_skip   = (const float*)d_in[12];
  const float* out_proj = (const float*)d_in[13];
  const float* norm_w   = (const float*)d_in[14];
  const float* norm_f_w = (const float*)d_in[15];
  const float* head_w   = (const float*)d_in[16];
  const float* head_b   = (const float*)d_in[17];
  float* out = (float*)d_out;

  float* ws = (float*)d_ws;
  float* residual = ws; ws += (long)L_SEQ * DM;
  float* hidden   = ws; ws += (long)L_SEQ * DM;
  float* hn       = ws; ws += (long)L_SEQ * DM;
  float* xz       = ws; ws += (long)L_SEQ * 2 * DI;
  float* xc       = ws; ws += (long)2 * L_SEQ * DI;
  float* dbl      = ws; ws += (long)2 * L_SEQ * 80;
  float* dtb      = ws; ws += (long)2 * L_SEQ * DI;
  float* yb       = ws; ws += (long)2 * L_SEQ * DI;
  float* part_h   = ws; ws += (long)2 * NC * DI * DSTATE;
  float* part_S   = ws; ws += (long)2 * NC * DI;

  patch_embed_kernel<<<dim3(3, L_SEQ), 256, 0, stream>>>(
      x, patch_w, patch_b, cls_tok, pos_emb, hidden, residual);

  for (int l = 0; l < DEPTH; ++l) {
    const float* ipw = in_proj  + (long)l * 2 * DI * DM;
    const float* cw  = conv_w   + (long)l * 2 * DI * 4;
    const float* cb  = conv_b   + (long)l * 2 * DI;
    const float* xw  = xproj_w  + (long)l * 2 * 80 * DI;
    const float* dw  = dtproj_w + (long)l * 2 * DI * DTRANK;
    const float* db  = dtproj_b + (long)l * 2 * DI;
    const float* Al  = A_log    + (long)l * 2 * DI * DSTATE;
    const float* Dk  = D_skip   + (long)l * 2 * DI;
    const float* opw = out_proj + (long)l * DM * DI;
    const float* nw  = norm_w   + (long)l * DM;

    rmsnorm_kernel<<<L_SEQ, 256, 0, stream>>>(hidden, residual, hn, nw);

    // xz(513,3072) = hn(513,768) @ ipw(3072,768)^T
    gemm_mfma<<<dim3(48, 9, 1), 256, 0, stream>>>(
        hn, nullptr, ipw, xz, L_SEQ, 2 * DI, DM, DM, DM, 2 * DI, 0, 0, 0,
        nullptr, 0, 0);

    conv_silu_kernel<<<dim3(3078, 2), 256, 0, stream>>>(xz, cw, cb, xc);

    // dbl(513,80) = xc(513,1536) @ xw(80,1536)^T  [batched over dir]
    gemm_mfma<<<dim3(2, 9, 2), 256, 0, stream>>>(
        xc, nullptr, xw, dbl, L_SEQ, 80, DI, DI, DI, 80,
        (long)L_SEQ * DI, (long)80 * DI, (long)L_SEQ * 80,
        nullptr, 0, 0);

    // dtb(513,1536) = softplus(dbl[:, :48] @ dw^T + db)  [batched]
    gemm_mfma<<<dim3(24, 9, 2), 256, 0, stream>>>(
        dbl, nullptr, dw, dtb, L_SEQ, DI, DTRANK, 80, DTRANK, DI,
        (long)L_SEQ * 80, (long)DI * DTRANK, (long)L_SEQ * DI,
        db, DI, 1);

    // chunked selective scan
    scan_part1<<<dim3(DI / 256, NC, 2), 256, 0, stream>>>(
        dtb, xc, dbl, Al, part_h, part_S);
    scan_fix<<<(2 * DI * DSTATE) / 256, 256, 0, stream>>>(Al, part_S, part_h);
    scan_part2<<<dim3(DI / 256, NC, 2), 256, 0, stream>>>(
        dtb, xc, dbl, xz, Al, Dk, part_h, yb);

    // hidden(513,768) = 0.5*(y0+y1)(513,1536) @ opw(768,1536)^T
    gemm_mfma<<<dim3(12, 9, 1), 256, 0, stream>>>(
        yb, yb + (long)L_SEQ * DI, opw, hidden,
        L_SEQ, DM, DI, DI, DI, DM, 0, 0, 0,
        nullptr, 0, 0);
  }

  head_kernel<<<NCLS, 256, 0, stream>>>(residual, hidden, norm_f_w, head_w, head_b, out);
}

// Round 4
// 3969.101 us; speedup vs baseline: 6.7640x; 1.4999x over previous
//
#include <hip/hip_runtime.h>

#define L_SEQ 513
#define DM 768
#define DI 1536
#define DSTATE 16
#define DTRANK 48
#define NCLS 527
#define DEPTH 24
#define NC 32     // time chunks for parallel scan
#define CLEN 17   // ceil(513/32); NC*CLEN = 544 >= 513

typedef unsigned short u16;
typedef __bf16 bf16x8 __attribute__((ext_vector_type(8)));
typedef float f32x4 __attribute__((ext_vector_type(4)));

#define MFMA_BF16(A, B, C) __builtin_amdgcn_mfma_f32_16x16x32_bf16(A, B, C, 0, 0, 0)

__device__ inline u16 f2bf(float x) {
  unsigned u = __float_as_uint(x);
  return (u16)((u + 0x7FFFu + ((u >> 16) & 1u)) >> 16);
}
__device__ inline float bf2f(u16 h) { return __uint_as_float((unsigned)h << 16); }
__device__ inline void split2(float v, u16& h, u16& l) {
  h = f2bf(v);
  l = f2bf(v - bf2f(h));
}

// ---------------- weight fp32 -> bf16 hi/lo splitter (grid-stride, float4) ----------------
__global__ void wconvert_kernel(const float* __restrict__ src,
                                u16* __restrict__ hi, u16* __restrict__ lo,
                                long n4) {
  long i = (long)blockIdx.x * 256 + threadIdx.x;
  long stride = (long)gridDim.x * 256;
  for (; i < n4; i += stride) {
    float4 v = ((const float4*)src)[i];
    ushort4 h, l;
    split2(v.x, h.x, l.x);
    split2(v.y, h.y, l.y);
    split2(v.z, h.z, l.z);
    split2(v.w, h.w, l.w);
    ((ushort4*)hi)[i] = h;
    ((ushort4*)lo)[i] = l;
  }
}

// ---------------- patch embed + cls insert + pos add ----------------
__global__ void patch_embed_kernel(const float* __restrict__ x,
                                   const float* __restrict__ pw,
                                   const float* __restrict__ pb,
                                   const float* __restrict__ cls,
                                   const float* __restrict__ pos,
                                   float* __restrict__ hidden,
                                   float* __restrict__ residual) {
  int c = blockIdx.x * 256 + threadIdx.x;
  int s = blockIdx.y;
  if (c >= DM) return;
  float val;
  if (s == 256) {
    val = cls[c];
  } else {
    int p = s - (s > 256 ? 1 : 0);
    int gy = p >> 6, gx = p & 63;
    const float* xp = x + gy * 16 * 1024 + gx * 16;
    const float* wp = pw + c * 256;
    float acc = pb[c];
#pragma unroll 4
    for (int ky = 0; ky < 16; ++ky)
#pragma unroll
      for (int kx = 0; kx < 16; ++kx)
        acc += xp[ky * 1024 + kx] * wp[ky * 16 + kx];
    val = acc;
  }
  long idx = (long)s * DM + c;
  hidden[idx] = val + pos[idx];
  residual[idx] = 0.f;
}

// ---------- residual += hidden; hn = rmsnorm(residual)*w -> bf16 hi/lo ----------
__global__ void rmsnorm_kernel(const float* __restrict__ hidden,
                               float* __restrict__ residual,
                               u16* __restrict__ hnh, u16* __restrict__ hnl,
                               const float* __restrict__ w) {
  int t = blockIdx.x;
  const float* hrow = hidden + (long)t * DM;
  float* rrow = residual + (long)t * DM;
  int tid = threadIdx.x;  // 256, DM = 3*256
  float vals[3];
  float ss = 0.f;
#pragma unroll
  for (int i = 0; i < 3; ++i) {
    int c = tid + i * 256;
    float v = rrow[c] + hrow[c];
    vals[i] = v;
    rrow[c] = v;
    ss += v * v;
  }
#pragma unroll
  for (int o = 32; o; o >>= 1) ss += __shfl_down(ss, o, 64);
  __shared__ float sacc[4];
  if ((tid & 63) == 0) sacc[tid >> 6] = ss;
  __syncthreads();
  float tot = sacc[0] + sacc[1] + sacc[2] + sacc[3];
  float rs = rsqrtf(tot / (float)DM + 1e-5f);
#pragma unroll
  for (int i = 0; i < 3; ++i) {
    int c = tid + i * 256;
    float y = vals[i] * rs * w[c];
    u16 h, l;
    split2(y, h, l);
    hnh[(long)t * DM + c] = h;
    hnl[(long)t * DM + c] = l;
  }
}

// ---------------- bf16 hi/lo MFMA GEMM: C = A*B^T, fp32-accurate ----------------
// A (M x K) as Ah/Al bf16 row-major lda; B (N x K) as Bh/Bl row-major ldb.
// C = Ah*Bh + Ah*Bl + Al*Bh. bias[n] optional; act==1: softplus.
// Chi/Clo != nullptr: also write bf16 hi/lo of C for n < ncap (stride ldhl).
__global__ __launch_bounds__(256) void gemm_hl(
    const u16* __restrict__ Ah, const u16* __restrict__ Al,
    const u16* __restrict__ Bh, const u16* __restrict__ Bl,
    float* __restrict__ C,
    int M, int N, int K, int lda, int ldb, int ldc,
    long sA, long sB, long sC,
    const float* __restrict__ bias, long sBias, int act,
    u16* __restrict__ Chi, u16* __restrict__ Clo, int ncap, int ldhl, long sChl) {
  int bz = blockIdx.z;
  const u16* Ahb = Ah + (long)bz * sA;
  const u16* Alb = Al + (long)bz * sA;
  const u16* Bhb = Bh + (long)bz * sB;
  const u16* Blb = Bl + (long)bz * sB;
  float* Cb = C + (long)bz * sC;
  const float* biasb = bias ? bias + (long)bz * sBias : nullptr;

  __shared__ u16 AhS[2][64 * 32], AlS[2][64 * 32];
  __shared__ u16 BhS[2][64 * 32], BlS[2][64 * 32];  // 32 KB total

  int tid = threadIdx.x;
  int m0 = blockIdx.y * 64, n0 = blockIdx.x * 64;

  // staging: thread -> (row, 8-element k-group)
  int srow = tid >> 2;  // 0..63
  int sg = tid & 3;     // 0..3
  int sIdx = srow * 32 + ((sg ^ ((srow >> 1) & 3)) << 3);
  int arow = m0 + srow, brow = n0 + srow;
  const u16* ah_p = Ahb + (long)arow * lda + sg * 8;
  const u16* al_p = Alb + (long)arow * lda + sg * 8;
  const u16* bh_p = Bhb + (long)brow * ldb + sg * 8;
  const u16* bl_p = Blb + (long)brow * ldb + sg * 8;
  bool aok = arow < M, bok = brow < N;

  // fragment mapping
  int lane = tid & 63;
  int w = tid >> 6;
  int wr = w >> 1, wc = w & 1;
  int fr = lane & 15, kh = lane >> 4;
  int rowA0 = wr * 32 + fr, rowA1 = rowA0 + 16;
  int rowB0 = wc * 32 + fr, rowB1 = rowB0 + 16;
  int offA0 = rowA0 * 32 + ((kh ^ ((rowA0 >> 1) & 3)) << 3);
  int offA1 = rowA1 * 32 + ((kh ^ ((rowA1 >> 1) & 3)) << 3);
  int offB0 = rowB0 * 32 + ((kh ^ ((rowB0 >> 1) & 3)) << 3);
  int offB1 = rowB1 * 32 + ((kh ^ ((rowB1 >> 1) & 3)) << 3);

  f32x4 acc00 = {0.f, 0.f, 0.f, 0.f}, acc01 = {0.f, 0.f, 0.f, 0.f};
  f32x4 acc10 = {0.f, 0.f, 0.f, 0.f}, acc11 = {0.f, 0.f, 0.f, 0.f};

  int nst = (K + 31) / 32;
  int kg = sg * 8;  // this thread's k offset within the 32-wide step

  uint4 ra, rl_, rb, rbl;
  {
    uint4 z = {0, 0, 0, 0};
    ra = (aok && kg + 8 <= K) ? *(const uint4*)ah_p : z;
    rl_ = (aok && kg + 8 <= K) ? *(const uint4*)al_p : z;
    rb = (bok && kg + 8 <= K) ? *(const uint4*)bh_p : z;
    rbl = (bok && kg + 8 <= K) ? *(const uint4*)bl_p : z;
  }
  *(uint4*)&AhS[0][sIdx] = ra;
  *(uint4*)&AlS[0][sIdx] = rl_;
  *(uint4*)&BhS[0][sIdx] = rb;
  *(uint4*)&BlS[0][sIdx] = rbl;

  for (int s = 0; s < nst; ++s) {
    if (s + 1 < nst) {
      int kb = (s + 1) * 32;
      uint4 z = {0, 0, 0, 0};
      bool kok = kb + kg + 8 <= K;
      ra = (aok && kok) ? *(const uint4*)(ah_p + kb) : z;
      rl_ = (aok && kok) ? *(const uint4*)(al_p + kb) : z;
      rb = (bok && kok) ? *(const uint4*)(bh_p + kb) : z;
      rbl = (bok && kok) ? *(const uint4*)(bl_p + kb) : z;
    }
    __syncthreads();
    int b = s & 1;

    bf16x8 ah0 = __builtin_bit_cast(bf16x8, *(const uint4*)&AhS[b][offA0]);
    bf16x8 ah1 = __builtin_bit_cast(bf16x8, *(const uint4*)&AhS[b][offA1]);
    bf16x8 al0 = __builtin_bit_cast(bf16x8, *(const uint4*)&AlS[b][offA0]);
    bf16x8 al1 = __builtin_bit_cast(bf16x8, *(const uint4*)&AlS[b][offA1]);
    bf16x8 bh0 = __builtin_bit_cast(bf16x8, *(const uint4*)&BhS[b][offB0]);
    bf16x8 bh1 = __builtin_bit_cast(bf16x8, *(const uint4*)&BhS[b][offB1]);
    bf16x8 bl0 = __builtin_bit_cast(bf16x8, *(const uint4*)&BlS[b][offB0]);
    bf16x8 bl1 = __builtin_bit_cast(bf16x8, *(const uint4*)&BlS[b][offB1]);

    acc00 = MFMA_BF16(ah0, bh0, acc00);
    acc00 = MFMA_BF16(ah0, bl0, acc00);
    acc00 = MFMA_BF16(al0, bh0, acc00);
    acc01 = MFMA_BF16(ah0, bh1, acc01);
    acc01 = MFMA_BF16(ah0, bl1, acc01);
    acc01 = MFMA_BF16(al0, bh1, acc01);
    acc10 = MFMA_BF16(ah1, bh0, acc10);
    acc10 = MFMA_BF16(ah1, bl0, acc10);
    acc10 = MFMA_BF16(al1, bh0, acc10);
    acc11 = MFMA_BF16(ah1, bh1, acc11);
    acc11 = MFMA_BF16(ah1, bl1, acc11);
    acc11 = MFMA_BF16(al1, bh1, acc11);

    if (s + 1 < nst) {
      int b2 = (s + 1) & 1;
      *(uint4*)&AhS[b2][sIdx] = ra;
      *(uint4*)&AlS[b2][sIdx] = rl_;
      *(uint4*)&BhS[b2][sIdx] = rb;
      *(uint4*)&BlS[b2][sIdx] = rbl;
    }
  }

  u16* Chib = Chi ? Chi + (long)bz * sChl : nullptr;
  u16* Clob = Clo ? Clo + (long)bz * sChl : nullptr;
  int mbase = m0 + wr * 32, nbase = n0 + wc * 32;
#define WRITE_FRAG(ACC, MI, NI)                                       \
  {                                                                   \
    int n = nbase + (NI)*16 + fr;                                     \
    if (n < N) {                                                      \
      float bv = biasb ? biasb[n] : 0.f;                              \
      _Pragma("unroll")                                               \
      for (int r = 0; r < 4; ++r) {                                   \
        int m = mbase + (MI)*16 + kh * 4 + r;                         \
        if (m < M) {                                                  \
          float v = ACC[r] + bv;                                      \
          if (act == 1) v = (v > 20.f) ? v : log1pf(__expf(v));       \
          Cb[(long)m * ldc + n] = v;                                  \
          if (Chib && n < ncap) {                                     \
            u16 hh, ll;                                               \
            split2(v, hh, ll);                                        \
            Chib[(long)m * ldhl + n] = hh;                            \
            Clob[(long)m * ldhl + n] = ll;                            \
          }                                                           \
        }                                                             \
      }                                                               \
    }                                                                 \
  }
  WRITE_FRAG(acc00, 0, 0)
  WRITE_FRAG(acc01, 0, 1)
  WRITE_FRAG(acc10, 1, 0)
  WRITE_FRAG(acc11, 1, 1)
#undef WRITE_FRAG
}

// -------- causal depthwise conv (D_CONV=4) + silu -> fp32 + bf16 hi/lo --------
__global__ void conv_silu_kernel(const float* __restrict__ xz,
                                 const float* __restrict__ cw,  // (2, DI, 4)
                                 const float* __restrict__ cb,  // (2, DI)
                                 float* __restrict__ xc,
                                 u16* __restrict__ xch, u16* __restrict__ xcl) {
  int dir = blockIdx.y;
  int idx = blockIdx.x * 256 + threadIdx.x;  // over L*DI, d fastest
  int d = idx % DI;
  int t = idx / DI;
  const float* w = cw + ((long)dir * DI + d) * 4;
  float acc = cb[dir * DI + d];
#pragma unroll
  for (int k = 0; k < 4; ++k) {
    int tau = t + k - 3;
    if (tau >= 0) {
      int tsrc = dir ? (L_SEQ - 1 - tau) : tau;
      acc += w[k] * xz[(long)tsrc * (2 * DI) + d];
    }
  }
  float s = acc / (1.f + __expf(-acc));
  long o = ((long)dir * L_SEQ + t) * DI + d;
  xc[o] = s;
  u16 h, l;
  split2(s, h, l);
  xch[o] = h;
  xcl[o] = l;
}

// ---------------- chunked selective scan, pass 1 ----------------
__global__ __launch_bounds__(256) void scan_part1(
    const float* __restrict__ dtv_arr,
    const float* __restrict__ xc,
    const float* __restrict__ dbl,   // (2, L, 80)
    const float* __restrict__ A_log, // (2, DI, 16)
    float* __restrict__ part_h,      // (2, NC, DI, 16)
    float* __restrict__ part_S) {    // (2, NC, DI)
  int dir = blockIdx.z;
  int c = blockIdx.y;
  int d = blockIdx.x * 256 + threadIdx.x;
  int t0 = c * CLEN;
  int t1 = min(t0 + CLEN, L_SEQ);

  __shared__ float Bs[CLEN][DSTATE];
  const float* dblp = dbl + (long)dir * L_SEQ * 80;
  for (int i = threadIdx.x; i < (t1 - t0) * DSTATE; i += 256) {
    int tt = i >> 4, n = i & 15;
    Bs[tt][n] = dblp[(long)(t0 + tt) * 80 + DTRANK + n];
  }
  __syncthreads();

  float negA[DSTATE], h[DSTATE];
#pragma unroll
  for (int n = 0; n < DSTATE; ++n) {
    negA[n] = -__expf(A_log[((long)dir * DI + d) * DSTATE + n]);
    h[n] = 0.f;
  }
  const float* dtp = dtv_arr + (long)dir * L_SEQ * DI;
  const float* xcp = xc + (long)dir * L_SEQ * DI;

  float S = 0.f;
  float dt_c = 0.f, u_c = 0.f;
  if (t0 < t1) {
    dt_c = dtp[(long)t0 * DI + d];
    u_c = xcp[(long)t0 * DI + d];
  }
  for (int t = t0; t < t1; ++t) {
    float dt_n = 0.f, u_n = 0.f;
    if (t + 1 < t1) {
      dt_n = dtp[(long)(t + 1) * DI + d];
      u_n = xcp[(long)(t + 1) * DI + d];
    }
    S += dt_c;
    float du = dt_c * u_c;
    int tt = t - t0;
#pragma unroll
    for (int n = 0; n < DSTATE; ++n)
      h[n] = h[n] * __expf(dt_c * negA[n]) + du * Bs[tt][n];
    dt_c = dt_n;
    u_c = u_n;
  }
  long base = ((long)dir * NC + c) * DI + d;
  part_S[base] = S;
#pragma unroll
  for (int n = 0; n < DSTATE; ++n) part_h[base * DSTATE + n] = h[n];
}

// ---------------- fix-up ----------------
__global__ void scan_fix(const float* __restrict__ A_log,
                         const float* __restrict__ part_S,
                         float* __restrict__ part_h) {
  int idx = blockIdx.x * 256 + threadIdx.x;  // (dir, d, n), n fastest
  int n = idx & 15;
  int d = (idx >> 4) % DI;
  int dir = (idx >> 4) / DI;
  float negA = -__expf(A_log[((long)dir * DI + d) * DSTATE + n]);
  float h = 0.f;
  for (int c = 0; c < NC; ++c) {
    long base = ((long)dir * NC + c) * DI + d;
    float S = part_S[base];
    float q = part_h[base * DSTATE + n];
    part_h[base * DSTATE + n] = h;
    h = h * __expf(negA * S) + q;
  }
}

// ---------------- pass 2: re-scan, emit gated y ----------------
__global__ __launch_bounds__(256) void scan_part2(
    const float* __restrict__ dtv_arr,
    const float* __restrict__ xc,
    const float* __restrict__ dbl,
    const float* __restrict__ xz,      // (L, 3072) for z
    const float* __restrict__ A_log,
    const float* __restrict__ Dsk,     // (2, DI)
    const float* __restrict__ part_h,  // hstart
    float* __restrict__ y) {           // (2, L_orig, DI)
  int dir = blockIdx.z;
  int c = blockIdx.y;
  int d = blockIdx.x * 256 + threadIdx.x;
  int t0 = c * CLEN;
  int t1 = min(t0 + CLEN, L_SEQ);

  __shared__ float Bs[CLEN][DSTATE];
  __shared__ float Cs[CLEN][DSTATE];
  const float* dblp = dbl + (long)dir * L_SEQ * 80;
  for (int i = threadIdx.x; i < (t1 - t0) * 2 * DSTATE; i += 256) {
    int tt = i >> 5, j = i & 31;
    float v = dblp[(long)(t0 + tt) * 80 + DTRANK + j];
    if (j < DSTATE) Bs[tt][j] = v; else Cs[tt][j - DSTATE] = v;
  }
  __syncthreads();

  float negA[DSTATE], h[DSTATE];
  long base = ((long)dir * NC + c) * DI + d;
#pragma unroll
  for (int n = 0; n < DSTATE; ++n) {
    negA[n] = -__expf(A_log[((long)dir * DI + d) * DSTATE + n]);
    h[n] = part_h[base * DSTATE + n];
  }
  float dskip = Dsk[dir * DI + d];
  const float* dtp = dtv_arr + (long)dir * L_SEQ * DI;
  const float* xcp = xc + (long)dir * L_SEQ * DI;

  float dt_c = 0.f, u_c = 0.f;
  if (t0 < t1) {
    dt_c = dtp[(long)t0 * DI + d];
    u_c = xcp[(long)t0 * DI + d];
  }
  for (int t = t0; t < t1; ++t) {
    float dt_n = 0.f, u_n = 0.f;
    if (t + 1 < t1) {
      dt_n = dtp[(long)(t + 1) * DI + d];
      u_n = xcp[(long)(t + 1) * DI + d];
    }
    float du = dt_c * u_c;
    int tt = t - t0;
    float acc = 0.f;
#pragma unroll
    for (int n = 0; n < DSTATE; ++n) {
      h[n] = h[n] * __expf(dt_c * negA[n]) + du * Bs[tt][n];
      acc += h[n] * Cs[tt][n];
    }
    int tsrc = dir ? (L_SEQ - 1 - t) : t;
    float zv = xz[(long)tsrc * (2 * DI) + DI + d];
    float sz = zv / (1.f + __expf(-zv));
    y[((long)dir * L_SEQ + tsrc) * DI + d] = (acc + dskip * u_c) * sz;
    dt_c = dt_n;
    u_c = u_n;
  }
}

// ---------------- (yf+yb)*0.5 -> bf16 hi/lo ----------------
__global__ void yavg_kernel(const float* __restrict__ yf,
                            const float* __restrict__ yb,
                            u16* __restrict__ yh, u16* __restrict__ yl) {
  long i = (long)blockIdx.x * 256 + threadIdx.x;
  if (i >= (long)L_SEQ * DI / 4) return;
  float4 a = ((const float4*)yf)[i];
  float4 b = ((const float4*)yb)[i];
  ushort4 h, l;
  split2(0.5f * (a.x + b.x), h.x, l.x);
  split2(0.5f * (a.y + b.y), h.y, l.y);
  split2(0.5f * (a.z + b.z), h.z, l.z);
  split2(0.5f * (a.w + b.w), h.w, l.w);
  ((ushort4*)yh)[i] = h;
  ((ushort4*)yl)[i] = l;
}

// ---------------- final rmsnorm(token 256) + head ----------------
__global__ void head_kernel(const float* __restrict__ residual,
                            const float* __restrict__ hidden,
                            const float* __restrict__ nfw,
                            const float* __restrict__ hw,
                            const float* __restrict__ hb,
                            float* __restrict__ out) {
  int j = blockIdx.x;
  int tid = threadIdx.x;  // 256
  const float* r = residual + (long)256 * DM;
  const float* h = hidden + (long)256 * DM;
  float ss = 0.f, dp = 0.f;
#pragma unroll
  for (int i = 0; i < 3; ++i) {
    int c = tid + i * 256;
    float v = r[c] + h[c];
    ss += v * v;
    dp += v * nfw[c] * hw[(long)j * DM + c];
  }
#pragma unroll
  for (int o = 32; o; o >>= 1) {
    ss += __shfl_down(ss, o, 64);
    dp += __shfl_down(dp, o, 64);
  }
  __shared__ float s1[4], s2[4];
  if ((tid & 63) == 0) {
    s1[tid >> 6] = ss;
    s2[tid >> 6] = dp;
  }
  __syncthreads();
  if (tid == 0) {
    float tot = s1[0] + s1[1] + s1[2] + s1[3];
    float d = s2[0] + s2[1] + s2[2] + s2[3];
    out[j] = d * rsqrtf(tot / (float)DM + 1e-5f) + hb[j];
  }
}

extern "C" void kernel_launch(void* const* d_in, const int* in_sizes, int n_in,
                              void* d_out, int out_size, void* d_ws, size_t ws_size,
                              hipStream_t stream) {
  const float* x        = (const float*)d_in[0];
  const float* patch_w  = (const float*)d_in[1];
  const float* patch_b  = (const float*)d_in[2];
  const float* cls_tok  = (const float*)d_in[3];
  const float* pos_emb  = (const float*)d_in[4];
  const float* in_proj  = (const float*)d_in[5];
  const float* conv_w   = (const float*)d_in[6];
  const float* conv_b   = (const float*)d_in[7];
  const float* xproj_w  = (const float*)d_in[8];
  const float* dtproj_w = (const float*)d_in[9];
  const float* dtproj_b = (const float*)d_in[10];
  const float* A_log    = (const float*)d_in[11];
  const float* D_skip   = (const float*)d_in[12];
  const float* out_proj = (const float*)d_in[13];
  const float* norm_w   = (const float*)d_in[14];
  const float* norm_f_w = (const float*)d_in[15];
  const float* head_w   = (const float*)d_in[16];
  const float* head_b   = (const float*)d_in[17];
  float* out = (float*)d_out;

  float* ws = (float*)d_ws;
  float* residual = ws; ws += (long)L_SEQ * DM;
  float* hidden   = ws; ws += (long)L_SEQ * DM;
  float* xz       = ws; ws += (long)L_SEQ * 2 * DI;
  float* xc       = ws; ws += (long)2 * L_SEQ * DI;
  float* dbl      = ws; ws += (long)2 * L_SEQ * 80;
  float* dtb      = ws; ws += (long)2 * L_SEQ * DI;
  float* yb       = ws; ws += (long)2 * L_SEQ * DI;
  float* part_h   = ws; ws += (long)2 * NC * DI * DSTATE;
  float* part_S   = ws; ws += (long)2 * NC * DI;

  u16* wsu = (u16*)ws;
  const long N_HN  = (long)L_SEQ * DM;
  const long N_XC  = (long)2 * L_SEQ * DI;
  const long N_D48 = (long)2 * L_SEQ * DTRANK;
  const long N_YA  = (long)L_SEQ * DI;
  const long N_WI  = (long)DEPTH * 2 * DI * DM;
  const long N_WX  = (long)DEPTH * 2 * 80 * DI;
  const long N_WD  = (long)DEPTH * 2 * DI * DTRANK;
  const long N_WO  = (long)DEPTH * DM * DI;
  u16* hn_h  = wsu; wsu += N_HN;
  u16* hn_l  = wsu; wsu += N_HN;
  u16* xc_h  = wsu; wsu += N_XC;
  u16* xc_l  = wsu; wsu += N_XC;
  u16* d48_h = wsu; wsu += N_D48;
  u16* d48_l = wsu; wsu += N_D48;
  u16* ya_h  = wsu; wsu += N_YA;
  u16* ya_l  = wsu; wsu += N_YA;
  u16* wi_h  = wsu; wsu += N_WI;
  u16* wi_l  = wsu; wsu += N_WI;
  u16* wx_h  = wsu; wsu += N_WX;
  u16* wx_l  = wsu; wsu += N_WX;
  u16* wd_h  = wsu; wsu += N_WD;
  u16* wd_l  = wsu; wsu += N_WD;
  u16* wo_h  = wsu; wsu += N_WO;
  u16* wo_l  = wsu; wsu += N_WO;

  // weight pre-split (once per launch)
  wconvert_kernel<<<2048, 256, 0, stream>>>(in_proj,  wi_h, wi_l, N_WI / 4);
  wconvert_kernel<<<512,  256, 0, stream>>>(xproj_w,  wx_h, wx_l, N_WX / 4);
  wconvert_kernel<<<512,  256, 0, stream>>>(dtproj_w, wd_h, wd_l, N_WD / 4);
  wconvert_kernel<<<2048, 256, 0, stream>>>(out_proj, wo_h, wo_l, N_WO / 4);

  patch_embed_kernel<<<dim3(3, L_SEQ), 256, 0, stream>>>(
      x, patch_w, patch_b, cls_tok, pos_emb, hidden, residual);

  for (int l = 0; l < DEPTH; ++l) {
    const u16* wih = wi_h + (long)l * 2 * DI * DM;
    const u16* wil = wi_l + (long)l * 2 * DI * DM;
    const u16* wxh = wx_h + (long)l * 2 * 80 * DI;
    const u16* wxl = wx_l + (long)l * 2 * 80 * DI;
    const u16* wdh = wd_h + (long)l * 2 * DI * DTRANK;
    const u16* wdl = wd_l + (long)l * 2 * DI * DTRANK;
    const u16* woh = wo_h + (long)l * DM * DI;
    const u16* wol = wo_l + (long)l * DM * DI;
    const float* cw  = conv_w   + (long)l * 2 * DI * 4;
    const float* cb  = conv_b   + (long)l * 2 * DI;
    const float* db  = dtproj_b + (long)l * 2 * DI;
    const float* Al  = A_log    + (long)l * 2 * DI * DSTATE;
    const float* Dk  = D_skip   + (long)l * 2 * DI;
    const float* nw  = norm_w   + (long)l * DM;

    rmsnorm_kernel<<<L_SEQ, 256, 0, stream>>>(hidden, residual, hn_h, hn_l, nw);

    // xz(513,3072) = hn @ ipw^T
    gemm_hl<<<dim3(48, 9, 1), 256, 0, stream>>>(
        hn_h, hn_l, wih, wil, xz, L_SEQ, 2 * DI, DM, DM, DM, 2 * DI, 0, 0, 0,
        nullptr, 0, 0, nullptr, nullptr, 0, 0, 0);

    conv_silu_kernel<<<dim3(3078, 2), 256, 0, stream>>>(xz, cw, cb, xc, xc_h, xc_l);

    // dbl(513,80) = xc @ xw^T  [batched over dir]; also emit hi/lo for n<48
    gemm_hl<<<dim3(2, 9, 2), 256, 0, stream>>>(
        xc_h, xc_l, wxh, wxl, dbl, L_SEQ, 80, DI, DI, DI, 80,
        (long)L_SEQ * DI, (long)80 * DI, (long)L_SEQ * 80,
        nullptr, 0, 0, d48_h, d48_l, DTRANK, DTRANK, (long)L_SEQ * DTRANK);

    // dtb(513,1536) = softplus(dbl48 @ dw^T + db)  [batched]
    gemm_hl<<<dim3(24, 9, 2), 256, 0, stream>>>(
        d48_h, d48_l, wdh, wdl, dtb, L_SEQ, DI, DTRANK, DTRANK, DTRANK, DI,
        (long)L_SEQ * DTRANK, (long)DI * DTRANK, (long)L_SEQ * DI,
        db, DI, 1, nullptr, nullptr, 0, 0, 0);

    // chunked selective scan
    scan_part1<<<dim3(DI / 256, NC, 2), 256, 0, stream>>>(
        dtb, xc, dbl, Al, part_h, part_S);
    scan_fix<<<(2 * DI * DSTATE) / 256, 256, 0, stream>>>(Al, part_S, part_h);
    scan_part2<<<dim3(DI / 256, NC, 2), 256, 0, stream>>>(
        dtb, xc, dbl, xz, Al, Dk, part_h, yb);

    // yavg = 0.5*(yf+yb) -> bf16 hi/lo
    yavg_kernel<<<(L_SEQ * DI / 4 + 255) / 256, 256, 0, stream>>>(
        yb, yb + (long)L_SEQ * DI, ya_h, ya_l);

    // hidden(513,768) = yavg @ opw^T
    gemm_hl<<<dim3(12, 9, 1), 256, 0, stream>>>(
        ya_h, ya_l, woh, wol, hidden, L_SEQ, DM, DI, DI, DI, DM, 0, 0, 0,
        nullptr, 0, 0, nullptr, nullptr, 0, 0, 0);
  }

  head_kernel<<<NCLS, 256, 0, stream>>>(residual, hidden, norm_f_w, head_w, head_b, out);
}